// Round 1
// baseline (92.457 us; speedup 1.0000x reference)
//
#include <hip/hip_runtime.h>
#include <hip/hip_bf16.h>

// memristor_dense: y[b,j] = sum_i A[i,2j]*2^(e[i,2j]*l[b,i]) - A[i,2j+1]*2^(e[i,2j+1]*l[b,i])
//   A[i,j] = 0.5*|w[i,j]| + max_w/18, e = log2(n_param)+1, l = log2(2*clip(x))
// shapes: x(128,1024), w_pos/w_neg(1024,512), b_pos/b_neg(512), n_param(1025,1024)
//
// R13 -> R14: main loop untouched. Replace the 2M device-scope atomicAdds
// (32 z-blocks x 64K outputs, cross-XCD RMW serialization) with non-atomic
// partial stores into d_ws (64 slabs x 64 rows x 512 j = 8MB) + a reduce
// kernel that sums the 32 z-partials per output. Also drops y-zeroing from
// setup (reduce fully overwrites y). Theory: loop models at ~10-12us; the
// missing ~70us is the atomic tail + setup->main y dependency.

#define LOG2F(v)  __builtin_amdgcn_logf(v)    // v_log_f32: log2(x)
#define EXP2F(v)  __builtin_amdgcn_exp2f(v)   // v_exp_f32: 2^x

#define NJ 16        // jpairs per block
#define NB 64        // batch rows per block (4 per thread)
#define KI 32        // i-rows per block (one chunk, z-split 32)
#define SLS4 17      // sL k-row stride in float4 (16 rows-of-4 + pad)
#define PART_OFF 1024  // float offset of partials inside ws (ws[0] = maxbits)

__global__ __launch_bounds__(256) void setup_kernel(
    const float* __restrict__ w_pos, const float* __restrict__ w_neg,
    const float* __restrict__ b_pos, const float* __restrict__ b_neg,
    int* __restrict__ ws) {
  const int t = threadIdx.x, blk = blockIdx.x;
  // |w| max partial: each array 131072 float4 -> 512 per block -> 2 per thread
  const float4* wp4 = (const float4*)w_pos;
  const float4* wn4 = (const float4*)w_neg;
  float m = 0.0f;
  #pragma unroll
  for (int r = 0; r < 2; ++r) {
    int i = blk * 512 + r * 256 + t;
    float4 a = wp4[i], b = wn4[i];
    m = fmaxf(m, fmaxf(fmaxf(fabsf(a.x), fabsf(a.y)), fmaxf(fabsf(a.z), fabsf(a.w))));
    m = fmaxf(m, fmaxf(fmaxf(fabsf(b.x), fabsf(b.y)), fmaxf(fabsf(b.z), fabsf(b.w))));
  }
  if (blk == 0) {
    m = fmaxf(m, fmaxf(fabsf(b_pos[t]), fabsf(b_pos[t + 256])));
    m = fmaxf(m, fmaxf(fabsf(b_neg[t]), fabsf(b_neg[t + 256])));
  }
  #pragma unroll
  for (int off = 32; off > 0; off >>= 1)
    m = fmaxf(m, __shfl_down(m, off, 64));
  __shared__ float sm[4];
  int lane = t & 63, wv = t >> 6;
  if (lane == 0) sm[wv] = m;
  __syncthreads();
  if (t == 0) {
    m = fmaxf(fmaxf(sm[0], sm[1]), fmaxf(sm[2], sm[3]));
    // positive-float bits compare correctly as int; poisoned 0xAAAAAAAA is
    // negative as int, so ws needs no initialization.
    atomicMax(ws, __float_as_int(m));
  }
}

__global__ __launch_bounds__(256) void memristor_kernel(
    const float* __restrict__ x, const float* __restrict__ w_pos,
    const float* __restrict__ w_neg, const float* __restrict__ b_pos,
    const float* __restrict__ b_neg, const float* __restrict__ n_param,
    float* __restrict__ ws) {
  __shared__ float2 sPa[KI * NJ];    // [k][jj] = {A0,E0}: 16 addrs x 8B = 32 banks, conflict-free
  __shared__ float2 sPb[KI * NJ];    // [k][jj] = {A1,E1}
  __shared__ float4 sL4[KI * SLS4];  // [k][row/4]; 4 addrs/wave, broadcast, free

  const float mw = __int_as_float(((const int*)ws)[0]);
  const float c0 = mw * (0.05f / 0.9f);   // G_MIN*V_REF/(K_V*k_G) = max_w/18

  const int j0 = blockIdx.x * NJ;   // 32 j-tiles
  const int b0 = blockIdx.y * NB;   // 2 b-tiles
  const int zt = blockIdx.z;        // 32-way i-split: rows [zt*32, zt*32+32)
  const int i0 = zt * KI;
  const int t  = threadIdx.x;
  const int jj = t & 15;
  const int bq = t >> 4;            // [0,16): rows 4bq..4bq+3

  const float2* np2 = (const float2*)n_param;

  // stage params k-major: 32 i x 16 j = 512 entries, 2 per thread
  #pragma unroll
  for (int r = 0; r < 2; ++r) {
    int il = r * 16 + (t >> 4);
    int jl = t & 15;
    int gi = i0 + il;
    float wp = w_pos[gi * 512 + j0 + jl];
    float wn = w_neg[gi * 512 + j0 + jl];
    float2 np = np2[gi * 512 + j0 + jl];
    sPa[il * NJ + jl] = make_float2(fmaf(0.5f, fabsf(wp), c0), LOG2F(np.x) + 1.0f);
    sPb[il * NJ + jl] = make_float2(fmaf(0.5f, fabsf(wn), c0), LOG2F(np.y) + 1.0f);
  }
  // stage x transposed: 64 rows x 32 k; coalesced float4 reads, scalar writes
  {
    float* sL = (float*)sL4;
    const float4* x4 = (const float4*)x;
    #pragma unroll
    for (int r = 0; r < 2; ++r) {
      int row = r * 32 + (t >> 3);
      int k4  = t & 7;
      float4 v = x4[(b0 + row) * 256 + zt * 8 + k4];
      v.x = fminf(fmaxf(v.x, 0.0f), 1.0f);
      v.y = fminf(fmaxf(v.y, 0.0f), 1.0f);
      v.z = fminf(fmaxf(v.z, 0.0f), 1.0f);
      v.w = fminf(fmaxf(v.w, 0.0f), 1.0f);
      sL[(4 * k4 + 0) * (4 * SLS4) + row] = LOG2F(2.0f * v.x);
      sL[(4 * k4 + 1) * (4 * SLS4) + row] = LOG2F(2.0f * v.y);
      sL[(4 * k4 + 2) * (4 * SLS4) + row] = LOG2F(2.0f * v.z);
      sL[(4 * k4 + 3) * (4 * SLS4) + row] = LOG2F(2.0f * v.w);
    }
  }
  __syncthreads();

  float a0 = 0.0f, a1 = 0.0f, a2 = 0.0f, a3 = 0.0f;
  #pragma unroll 4
  for (int k = 0; k < KI; ++k) {
    float2 pa = sPa[k * NJ + jj];          // b64, conflict-free
    float2 pb = sPb[k * NJ + jj];          // b64, conflict-free
    float4 l  = sL4[k * SLS4 + bq];        // b128, 4 addrs, broadcast
    a0 = fmaf(pa.x, EXP2F(pa.y * l.x), fmaf(-pb.x, EXP2F(pb.y * l.x), a0));
    a1 = fmaf(pa.x, EXP2F(pa.y * l.y), fmaf(-pb.x, EXP2F(pb.y * l.y), a1));
    a2 = fmaf(pa.x, EXP2F(pa.y * l.z), fmaf(-pb.x, EXP2F(pb.y * l.z), a2));
    a3 = fmaf(pa.x, EXP2F(pa.y * l.w), fmaf(-pb.x, EXP2F(pb.y * l.w), a3));
  }

  if (zt == 31) {
    // bias row i = 1024: inp = 1 -> vr = 2 -> 2^e; same for every b row
    int jg = j0 + jj;
    float2 np = np2[1024 * 512 + jg];
    float p0 = fmaf(0.5f, fabsf(b_pos[jg]), c0);
    float p1 = fmaf(0.5f, fabsf(b_neg[jg]), c0);
    float bias = p0 * EXP2F(LOG2F(np.x) + 1.0f) - p1 * EXP2F(LOG2F(np.y) + 1.0f);
    a0 += bias; a1 += bias; a2 += bias; a3 += bias;
  }

  // non-atomic partial store: slab s = by*32 + zt, 64x512 f32 per slab.
  // 64 lanes = 4 rows x 16 consecutive j -> 4x64B segments per store instr.
  float* part = ((float*)ws) + PART_OFF;
  const int s = blockIdx.y * 32 + zt;
  float* p = part + (s * 64 + 4 * bq) * 512 + j0 + jj;
  p[0 * 512] = a0;
  p[1 * 512] = a1;
  p[2 * 512] = a2;
  p[3 * 512] = a3;
}

__global__ __launch_bounds__(256) void reduce_kernel(
    const float* __restrict__ ws, float* __restrict__ y) {
  const float* part = ws + PART_OFF;
  const int g = blockIdx.x * 256 + threadIdx.x;  // [0, 65536): b = g>>9, j = g&511
  const int b = g >> 9;
  const int j = g & 511;
  const int by = b >> 6;         // which b-tile (blockIdx.y of main kernel)
  const int r  = b & 63;         // row within tile
  // slab s = by*32 + z; element (r, j); stride between z-slabs = 64*512
  const float* p = part + (by * 2048 + r) * 512 + j;
  float s0 = 0.0f, s1 = 0.0f, s2 = 0.0f, s3 = 0.0f;
  #pragma unroll
  for (int z = 0; z < 32; z += 4) {
    s0 += p[(z + 0) * 32768];
    s1 += p[(z + 1) * 32768];
    s2 += p[(z + 2) * 32768];
    s3 += p[(z + 3) * 32768];
  }
  y[g] = (s0 + s1) + (s2 + s3);
}

extern "C" void kernel_launch(void* const* d_in, const int* in_sizes, int n_in,
                              void* d_out, int out_size, void* d_ws, size_t ws_size,
                              hipStream_t stream) {
  const float* x       = (const float*)d_in[0];
  const float* w_pos   = (const float*)d_in[1];
  const float* w_neg   = (const float*)d_in[2];
  const float* b_pos   = (const float*)d_in[3];
  const float* b_neg   = (const float*)d_in[4];
  const float* n_param = (const float*)d_in[5];
  float* y   = (float*)d_out;

  setup_kernel<<<dim3(256), dim3(256), 0, stream>>>(
      w_pos, w_neg, b_pos, b_neg, (int*)d_ws);

  memristor_kernel<<<dim3(32, 2, 32), dim3(256), 0, stream>>>(
      x, w_pos, w_neg, b_pos, b_neg, n_param, (float*)d_ws);

  reduce_kernel<<<dim3(256), dim3(256), 0, stream>>>(
      (const float*)d_ws, y);
}

// Round 2
// 87.532 us; speedup vs baseline: 1.0563x; 1.0563x over previous
//
#include <hip/hip_runtime.h>
#include <hip/hip_bf16.h>

// memristor_dense: y[b,j] = sum_i A[i,2j]*2^(e[i,2j]*l[b,i]) - A[i,2j+1]*2^(e[i,2j+1]*l[b,i])
//   A[i,j] = 0.5*|w[i,j]| + max_w/18, e = log2(n_param)+1, l = log2(2*clip(x))
// shapes: x(128,1024), w_pos/w_neg(1024,512), b_pos/b_neg(512), n_param(1025,1024)
//
// R14 -> R15: REVERT to R13 (atomic output, 2 kernels, measured 87.4us).
// R14's partial-store+reduce experiment REGRESSED (+5us): atomics were never
// the bottleneck. Decomposition from profile arithmetic: dur_us includes the
// harness's two 256MiB workspace poison fills (~41us each, 82us fixed floor);
// our kernels total ~5us (R13: 87.4 = 82 + 5.4; R12 spills: 82 + 15.5 = 3.2x
// spill penalty on a ~4.5us main loop -- consistent). The main loop is at its
// trans-pipe roofline: 134M v_exp_f32 / (256 CU x 32 exp/cyc @ 2.4GHz) = 6.8us
// floor, overlapped with LDS (~6.8us/CU) and VALU. Nothing left >1us kernel-side.

#define LOG2F(v)  __builtin_amdgcn_logf(v)    // v_log_f32: log2(x)
#define EXP2F(v)  __builtin_amdgcn_exp2f(v)   // v_exp_f32: 2^x

#define NJ 16        // jpairs per block
#define NB 64        // batch rows per block (4 per thread)
#define KI 32        // i-rows per block (one chunk, z-split 32)
#define SLS4 17      // sL k-row stride in float4 (16 rows-of-4 + pad)

__global__ __launch_bounds__(256) void setup_kernel(
    const float* __restrict__ w_pos, const float* __restrict__ w_neg,
    const float* __restrict__ b_pos, const float* __restrict__ b_neg,
    float* __restrict__ y, int* __restrict__ ws) {
  const int t = threadIdx.x, blk = blockIdx.x;
  // zero d_out: 16384 float4 over 256 blocks = 64 per block
  float4* y4 = (float4*)y;
  if (t < 64) y4[blk * 64 + t] = make_float4(0.f, 0.f, 0.f, 0.f);
  // |w| max partial: each array 131072 float4 -> 512 per block -> 2 per thread
  const float4* wp4 = (const float4*)w_pos;
  const float4* wn4 = (const float4*)w_neg;
  float m = 0.0f;
  #pragma unroll
  for (int r = 0; r < 2; ++r) {
    int i = blk * 512 + r * 256 + t;
    float4 a = wp4[i], b = wn4[i];
    m = fmaxf(m, fmaxf(fmaxf(fabsf(a.x), fabsf(a.y)), fmaxf(fabsf(a.z), fabsf(a.w))));
    m = fmaxf(m, fmaxf(fmaxf(fabsf(b.x), fabsf(b.y)), fmaxf(fabsf(b.z), fabsf(b.w))));
  }
  if (blk == 0) {
    m = fmaxf(m, fmaxf(fabsf(b_pos[t]), fabsf(b_pos[t + 256])));
    m = fmaxf(m, fmaxf(fabsf(b_neg[t]), fabsf(b_neg[t + 256])));
  }
  #pragma unroll
  for (int off = 32; off > 0; off >>= 1)
    m = fmaxf(m, __shfl_down(m, off, 64));
  __shared__ float sm[4];
  int lane = t & 63, wv = t >> 6;
  if (lane == 0) sm[wv] = m;
  __syncthreads();
  if (t == 0) {
    m = fmaxf(fmaxf(sm[0], sm[1]), fmaxf(sm[2], sm[3]));
    // positive-float bits compare correctly as int; poisoned 0xAAAAAAAA is
    // negative as int, so ws needs no initialization.
    atomicMax(ws, __float_as_int(m));
  }
}

__global__ __launch_bounds__(256) void memristor_kernel(
    const float* __restrict__ x, const float* __restrict__ w_pos,
    const float* __restrict__ w_neg, const float* __restrict__ b_pos,
    const float* __restrict__ b_neg, const float* __restrict__ n_param,
    const float* __restrict__ ws, float* __restrict__ y) {
  __shared__ float2 sPa[KI * NJ];    // [k][jj] = {A0,E0}: 16 addrs x 8B = 32 banks, conflict-free
  __shared__ float2 sPb[KI * NJ];    // [k][jj] = {A1,E1}
  __shared__ float4 sL4[KI * SLS4];  // [k][row/4]; 4 addrs/wave, broadcast, free

  const float mw = __int_as_float(((const int*)ws)[0]);
  const float c0 = mw * (0.05f / 0.9f);   // G_MIN*V_REF/(K_V*k_G) = max_w/18

  const int j0 = blockIdx.x * NJ;   // 32 j-tiles
  const int b0 = blockIdx.y * NB;   // 2 b-tiles
  const int zt = blockIdx.z;        // 32-way i-split: rows [zt*32, zt*32+32)
  const int i0 = zt * KI;
  const int t  = threadIdx.x;
  const int jj = t & 15;
  const int bq = t >> 4;            // [0,16): rows 4bq..4bq+3

  const float2* np2 = (const float2*)n_param;

  // stage params k-major: 32 i x 16 j = 512 entries, 2 per thread
  #pragma unroll
  for (int r = 0; r < 2; ++r) {
    int il = r * 16 + (t >> 4);
    int jl = t & 15;
    int gi = i0 + il;
    float wp = w_pos[gi * 512 + j0 + jl];
    float wn = w_neg[gi * 512 + j0 + jl];
    float2 np = np2[gi * 512 + j0 + jl];
    sPa[il * NJ + jl] = make_float2(fmaf(0.5f, fabsf(wp), c0), LOG2F(np.x) + 1.0f);
    sPb[il * NJ + jl] = make_float2(fmaf(0.5f, fabsf(wn), c0), LOG2F(np.y) + 1.0f);
  }
  // stage x transposed: 64 rows x 32 k; coalesced float4 reads, scalar writes
  {
    float* sL = (float*)sL4;
    const float4* x4 = (const float4*)x;
    #pragma unroll
    for (int r = 0; r < 2; ++r) {
      int row = r * 32 + (t >> 3);
      int k4  = t & 7;
      float4 v = x4[(b0 + row) * 256 + zt * 8 + k4];
      v.x = fminf(fmaxf(v.x, 0.0f), 1.0f);
      v.y = fminf(fmaxf(v.y, 0.0f), 1.0f);
      v.z = fminf(fmaxf(v.z, 0.0f), 1.0f);
      v.w = fminf(fmaxf(v.w, 0.0f), 1.0f);
      sL[(4 * k4 + 0) * (4 * SLS4) + row] = LOG2F(2.0f * v.x);
      sL[(4 * k4 + 1) * (4 * SLS4) + row] = LOG2F(2.0f * v.y);
      sL[(4 * k4 + 2) * (4 * SLS4) + row] = LOG2F(2.0f * v.z);
      sL[(4 * k4 + 3) * (4 * SLS4) + row] = LOG2F(2.0f * v.w);
    }
  }
  __syncthreads();

  float a0 = 0.0f, a1 = 0.0f, a2 = 0.0f, a3 = 0.0f;
  #pragma unroll 4
  for (int k = 0; k < KI; ++k) {
    float2 pa = sPa[k * NJ + jj];          // b64, conflict-free
    float2 pb = sPb[k * NJ + jj];          // b64, conflict-free
    float4 l  = sL4[k * SLS4 + bq];        // b128, 4 addrs, broadcast
    a0 = fmaf(pa.x, EXP2F(pa.y * l.x), fmaf(-pb.x, EXP2F(pb.y * l.x), a0));
    a1 = fmaf(pa.x, EXP2F(pa.y * l.y), fmaf(-pb.x, EXP2F(pb.y * l.y), a1));
    a2 = fmaf(pa.x, EXP2F(pa.y * l.z), fmaf(-pb.x, EXP2F(pb.y * l.z), a2));
    a3 = fmaf(pa.x, EXP2F(pa.y * l.w), fmaf(-pb.x, EXP2F(pb.y * l.w), a3));
  }

  if (zt == 31) {
    // bias row i = 1024: inp = 1 -> vr = 2 -> 2^e; same for every b row
    int jg = j0 + jj;
    float2 np = np2[1024 * 512 + jg];
    float p0 = fmaf(0.5f, fabsf(b_pos[jg]), c0);
    float p1 = fmaf(0.5f, fabsf(b_neg[jg]), c0);
    float bias = p0 * EXP2F(LOG2F(np.x) + 1.0f) - p1 * EXP2F(LOG2F(np.y) + 1.0f);
    a0 += bias; a1 += bias; a2 += bias; a3 += bias;
  }

  const int row0 = b0 + 4 * bq;
  atomicAdd(&y[(row0 + 0) * 512 + j0 + jj], a0);
  atomicAdd(&y[(row0 + 1) * 512 + j0 + jj], a1);
  atomicAdd(&y[(row0 + 2) * 512 + j0 + jj], a2);
  atomicAdd(&y[(row0 + 3) * 512 + j0 + jj], a3);
}

extern "C" void kernel_launch(void* const* d_in, const int* in_sizes, int n_in,
                              void* d_out, int out_size, void* d_ws, size_t ws_size,
                              hipStream_t stream) {
  const float* x       = (const float*)d_in[0];
  const float* w_pos   = (const float*)d_in[1];
  const float* w_neg   = (const float*)d_in[2];
  const float* b_pos   = (const float*)d_in[3];
  const float* b_neg   = (const float*)d_in[4];
  const float* n_param = (const float*)d_in[5];
  float* y   = (float*)d_out;

  setup_kernel<<<dim3(256), dim3(256), 0, stream>>>(
      w_pos, w_neg, b_pos, b_neg, y, (int*)d_ws);

  memristor_kernel<<<dim3(32, 2, 32), dim3(256), 0, stream>>>(
      x, w_pos, w_neg, b_pos, b_neg, n_param, (const float*)d_ws, y);
}